// Round 2
// baseline (69.399 us; speedup 1.0000x reference)
//
#include <hip/hip_runtime.h>
#include <hip/hip_bf16.h>

// Closed-form (num_layers == 1, the shipped problem shape):
//   E_q = cos(x_q + theta_q)
//   out0 = E1*E2*E3, out1 = E0*E1, out2 = E0*E1*E2, out3 = E0*E1*E2*E3
// Derivation: after encoding RY + layer RY each qubit is an independent
// product state with <(-1)^{y_q}> = cos(x_q+theta_q); the CNOT ring is a
// classical bit permutation z0=y1^y2^y3, z1=y0^y1, z2=y0^y1^y2,
// z3=y0^y1^y2^y3, and expectations factorize by independence.
//
// Streaming shape: 1 float4 in + 1 float4 out per sample, 32 MB total.
// VPT float4s per thread for ILP; N = 2^20 samples divisible by 256*VPT.
constexpr int VPT = 2;

__global__ __launch_bounds__(256) void qexp_closed_kernel(
    const float4* __restrict__ x, const float4* __restrict__ params,
    float4* __restrict__ out, int n) {
  float4 p = params[0];  // uniform -> scalar loads
  int base = (blockIdx.x * blockDim.x + threadIdx.x) * VPT;
  float4 xi[VPT];
#pragma unroll
  for (int v = 0; v < VPT; ++v) xi[v] = x[base + v];  // independent loads, ILP
#pragma unroll
  for (int v = 0; v < VPT; ++v) {
    float e0 = __cosf(xi[v].x + p.x);
    float e1 = __cosf(xi[v].y + p.y);
    float e2 = __cosf(xi[v].z + p.z);
    float e3 = __cosf(xi[v].w + p.w);
    float4 o;
    o.y = e0 * e1;
    o.x = e1 * e2 * e3;
    o.z = o.y * e2;
    o.w = o.z * e3;
    out[base + v] = o;
  }
}

// Tail-safe variant for n not divisible by 256*VPT (not hit at shipped shape).
__global__ __launch_bounds__(256) void qexp_closed_tail_kernel(
    const float4* __restrict__ x, const float4* __restrict__ params,
    float4* __restrict__ out, int n) {
  float4 p = params[0];
  int i = blockIdx.x * blockDim.x + threadIdx.x;
  if (i >= n) return;
  float4 xi = x[i];
  float e0 = __cosf(xi.x + p.x);
  float e1 = __cosf(xi.y + p.y);
  float e2 = __cosf(xi.z + p.z);
  float e3 = __cosf(xi.w + p.w);
  float4 o;
  o.y = e0 * e1;
  o.x = e1 * e2 * e3;
  o.z = o.y * e2;
  o.w = o.z * e3;
  out[i] = o;
}

// Generic fallback: full 16-amplitude statevector in registers, arbitrary
// number of BasicEntanglerLayers. Wire 0 = most significant bit (bit 3-q).
__global__ __launch_bounds__(256) void qsim_generic_kernel(
    const float4* __restrict__ x, const float* __restrict__ params,
    float4* __restrict__ out, int n, int layers) {
  int i = blockIdx.x * blockDim.x + threadIdx.x;
  if (i >= n) return;
  float4 xi = x[i];
  float ang[4] = {xi.x, xi.y, xi.z, xi.w};
  float st[16];
#pragma unroll
  for (int k = 0; k < 16; ++k) st[k] = 0.f;
  st[0] = 1.f;
#pragma unroll
  for (int q = 0; q < 4; ++q) {
    float c = __cosf(0.5f * ang[q]);
    float s = __sinf(0.5f * ang[q]);
    int mask = 1 << (3 - q);
#pragma unroll
    for (int k = 0; k < 16; ++k) {
      if (!(k & mask)) {
        float a0 = st[k], a1 = st[k | mask];
        st[k] = c * a0 - s * a1;
        st[k | mask] = s * a0 + c * a1;
      }
    }
  }
  for (int l = 0; l < layers; ++l) {
#pragma unroll
    for (int q = 0; q < 4; ++q) {
      float t = params[l * 4 + q];
      float c = __cosf(0.5f * t);
      float s = __sinf(0.5f * t);
      int mask = 1 << (3 - q);
#pragma unroll
      for (int k = 0; k < 16; ++k) {
        if (!(k & mask)) {
          float a0 = st[k], a1 = st[k | mask];
          st[k] = c * a0 - s * a1;
          st[k | mask] = s * a0 + c * a1;
        }
      }
    }
#pragma unroll
    for (int q = 0; q < 4; ++q) {
      int cm = 1 << (3 - q);
      int tm = 1 << (3 - ((q + 1) & 3));
#pragma unroll
      for (int k = 0; k < 16; ++k) {
        if ((k & cm) && !(k & tm)) {
          float tmp = st[k];
          st[k] = st[k | tm];
          st[k | tm] = tmp;
        }
      }
    }
  }
  float4 o = {0.f, 0.f, 0.f, 0.f};
#pragma unroll
  for (int k = 0; k < 16; ++k) {
    float p = st[k] * st[k];
    o.x += (k & 8) ? -p : p;
    o.y += (k & 4) ? -p : p;
    o.z += (k & 2) ? -p : p;
    o.w += (k & 1) ? -p : p;
  }
  out[i] = o;
}

extern "C" void kernel_launch(void* const* d_in, const int* in_sizes, int n_in,
                              void* d_out, int out_size, void* d_ws, size_t ws_size,
                              hipStream_t stream) {
  const float* params = (const float*)d_in[1];
  float4* out = (float4*)d_out;
  int n = in_sizes[0] / 4;  // samples
  if (in_sizes[1] == 4) {
    if (n % (256 * VPT) == 0) {
      int blocks = n / (256 * VPT);
      qexp_closed_kernel<<<blocks, 256, 0, stream>>>(
          (const float4*)d_in[0], (const float4*)params, out, n);
    } else {
      int blocks = (n + 255) / 256;
      qexp_closed_tail_kernel<<<blocks, 256, 0, stream>>>(
          (const float4*)d_in[0], (const float4*)params, out, n);
    }
  } else {
    int layers = in_sizes[1] / 4;
    int blocks = (n + 255) / 256;
    qsim_generic_kernel<<<blocks, 256, 0, stream>>>(
        (const float4*)d_in[0], params, out, n, layers);
  }
}